// Round 8
// baseline (209.941 us; speedup 1.0000x reference)
//
#include <hip/hip_runtime.h>
#include <hip/hip_bf16.h>
#include <stdint.h>

typedef unsigned short u16;
typedef __attribute__((ext_vector_type(8))) short short8;
typedef __attribute__((ext_vector_type(4))) float floatx4;

#define N_IMG 4
#define C_IN  2048
#define HW    1024
#define KK    9
#define O_OUT 256
#define NPIX  4096          // N_IMG*HW
#define M_PAD  2432         // 19*128 (2304 proj rows + 81 conv + pad)
#define K_DIM  2048
#define BN_EPS 1e-5f

#define SZ_A   ((size_t)M_PAD * K_DIM * 2)      // 9,961,472
#define SZ_XT  ((size_t)NPIX * K_DIM * 2)       // 16,777,216
#define SZ_H   ((size_t)M_PAD * NPIX * 2)       // 19,922,944
#define SZ_SRAW ((size_t)N_IMG * KK * HW * 4)   // 147,456

// fp32 -> bf16 bits, round-to-nearest-even
__device__ __forceinline__ u16 f2b(float f) {
    unsigned u = __float_as_uint(f);
    return (u16)((u + 0x7FFFu + ((u >> 16) & 1u)) >> 16);
}

__device__ __forceinline__ void load8f(const float* base, size_t eidx, u16* out) {
    const float* p = base + eidx;
    float4 a = ((const float4*)p)[0];
    float4 b = ((const float4*)p)[1];
    float f[8] = {a.x, a.y, a.z, a.w, b.x, b.y, b.z, b.w};
#pragma unroll
    for (int j = 0; j < 8; ++j) out[j] = f2b(f[j]);
}

// ---------------- merged staging kernel ----------------
// blocks [0,2048): transpose x -> XT, u32-packed LDS (2-way conflicts max)
// blocks [2048,2304): A proj rows; [2304,2313): A conv rows; 2313: zero-pad + stats
__global__ void build_all(const float* __restrict__ x, const float* __restrict__ wgt,
                          const float* __restrict__ cw, u16* __restrict__ xt,
                          u16* __restrict__ A, float* __restrict__ stats) {
    __shared__ __align__(16) u16 lds[9 * 2056];
    int b = blockIdx.x, t = threadIdx.x;
    if (b < 2048) {
        int c0 = (b & 31) * 64, p0 = ((b >> 5) & 15) * 64, n = b >> 9;
        int rp = t >> 3;                // channel-pair 0..31
        int pv = (t & 7) * 8;           // pixel group
        u16 h0[8], h1[8];
        load8f(x, (size_t)(n * C_IN + c0 + 2 * rp) * HW + p0 + pv, h0);
        load8f(x, (size_t)(n * C_IN + c0 + 2 * rp + 1) * HW + p0 + pv, h1);
        unsigned* l32 = (unsigned*)lds;   // [64 pixels][stride 35 u32], 8.96 KB
#pragma unroll
        for (int j = 0; j < 8; ++j)
            l32[(pv + j) * 35 + rp] = (unsigned)h0[j] | ((unsigned)h1[j] << 16);
        __syncthreads();
        int pr = t >> 3, cq = (t & 7) * 4;   // pixel, u32-quad (8 channels)
        unsigned o0[4], o1[4];
#pragma unroll
        for (int i = 0; i < 4; ++i) {
            o0[i] = l32[pr * 35 + cq + i];
            o1[i] = l32[(pr + 32) * 35 + cq + i];
        }
        *(uint4*)(xt + (size_t)(n * HW + p0 + pr) * K_DIM + c0 + cq * 2) = *(uint4*)o0;
        *(uint4*)(xt + (size_t)(n * HW + p0 + pr + 32) * K_DIM + c0 + cq * 2) = *(uint4*)o1;
    } else if (b < 2304) {
        int o = b - 2048;
        size_t base = (size_t)o * 18432;   // weight[o][c][l], e = c*9+l
        for (int i = 0; i < 9; ++i) {
            int e0 = (t + i * 256) * 8;
            u16 hv[8];
            load8f(wgt, base + e0, hv);
#pragma unroll
            for (int j = 0; j < 8; ++j) {
                int e = e0 + j;
                int c = e / 9, l = e - c * 9;
                lds[l * 2056 + c] = hv[j];
            }
        }
        __syncthreads();
        for (int l = 0; l < 9; ++l) {
            size_t row = (size_t)l * 256 + o;
            *(uint4*)(A + row * K_DIM + t * 8) = *(const uint4*)&lds[l * 2056 + t * 8];
        }
    } else if (b < 2313) {
        int l = b - 2304;
        size_t base = (size_t)l * 18432;    // conv_w[l][c][k], e = c*9+k
        for (int i = 0; i < 9; ++i) {
            int e0 = (t + i * 256) * 8;
            u16 hv[8];
            load8f(cw, base + e0, hv);
#pragma unroll
            for (int j = 0; j < 8; ++j) {
                int e = e0 + j;
                int c = e / 9, k = e - c * 9;
                lds[k * 2056 + c] = hv[j];
            }
        }
        __syncthreads();
        for (int k = 0; k < 9; ++k) {
            size_t row = 2304 + (size_t)k * 9 + l;
            *(uint4*)(A + row * K_DIM + t * 8) = *(const uint4*)&lds[k * 2056 + t * 8];
        }
    } else {
        uint4 z = {0, 0, 0, 0};
        uint4* dst = (uint4*)(A + (size_t)2385 * K_DIM);
        for (int i = t; i < (47 * 2048) / 8; i += 256) dst[i] = z;
        if (t < 18) stats[t] = 0.0f;
    }
}

// ---------------- GEMM: H = A * XT^T, 128x128 tiles, optional split-K x2 ----------------
__device__ __forceinline__ void gload_lds16(const void* g, void* l) {
    __builtin_amdgcn_global_load_lds((__attribute__((address_space(1))) void*)(g),
                                     (__attribute__((address_space(3))) void*)(l), 16, 0, 0);
}

__global__ void gemm_bt(const u16* __restrict__ A, const u16* __restrict__ B,
                        __hip_bfloat16* __restrict__ C, int split) {
    __shared__ __align__(16) u16 As[128 * 32];
    __shared__ __align__(16) u16 Bs[128 * 32];
    int bx = blockIdx.x;
    int tile, kbase, iters;
    __hip_bfloat16* Cw;
    if (split) {
        int ks = bx & 1; tile = bx >> 1;
        kbase = ks * (K_DIM / 2); iters = K_DIM / 64;
        Cw = C + (size_t)ks * M_PAD * NPIX;
    } else {
        tile = bx; kbase = 0; iters = K_DIM / 32; Cw = C;
    }
    int mt = tile % 19, nt = tile / 19;
    int m0 = mt * 128, n0 = nt * 128;
    int t = threadIdx.x;
    int w = t >> 6, lam = t & 63;
    int wm = w >> 1, wn = w & 1;
    int lm = lam & 15, q = lam >> 4;

    floatx4 acc[4][4];
    floatx4 z = {0.f, 0.f, 0.f, 0.f};
#pragma unroll
    for (int i = 0; i < 4; ++i)
#pragma unroll
        for (int j = 0; j < 4; ++j) acc[i][j] = z;

    int c0 = w, c1 = w + 4;
    int rrow0 = c0 * 16 + (lam >> 2);
    int rrow1 = c1 * 16 + (lam >> 2);
    int kc = (lam & 3) * 8;
    const u16* gA0 = A + (size_t)(m0 + rrow0) * K_DIM + kbase + kc;
    const u16* gA1 = A + (size_t)(m0 + rrow1) * K_DIM + kbase + kc;
    const u16* gB0 = B + (size_t)(n0 + rrow0) * K_DIM + kbase + kc;
    const u16* gB1 = B + (size_t)(n0 + rrow1) * K_DIM + kbase + kc;
    u16* lA0 = As + c0 * 512;  u16* lA1 = As + c1 * 512;
    u16* lB0 = Bs + c0 * 512;  u16* lB1 = Bs + c1 * 512;

    for (int kt = 0; kt < iters; ++kt) {
        gload_lds16(gA0, lA0);
        gload_lds16(gA1, lA1);
        gload_lds16(gB0, lB0);
        gload_lds16(gB1, lB1);
        gA0 += 32; gA1 += 32; gB0 += 32; gB1 += 32;
        __syncthreads();
        short8 af[4], bf[4];
#pragma unroll
        for (int i = 0; i < 4; ++i)
            af[i] = *(const short8*)(As + (wm * 64 + i * 16 + lm) * 32 + q * 8);
#pragma unroll
        for (int j = 0; j < 4; ++j)
            bf[j] = *(const short8*)(Bs + (wn * 64 + j * 16 + lm) * 32 + q * 8);
#pragma unroll
        for (int i = 0; i < 4; ++i)
#pragma unroll
            for (int j = 0; j < 4; ++j)
                acc[i][j] = __builtin_amdgcn_mfma_f32_16x16x32_bf16(af[i], bf[j], acc[i][j], 0, 0, 0);
        __syncthreads();
    }
    // C/D layout: col=lane&15, row=(lane>>4)*4+reg
#pragma unroll
    for (int i = 0; i < 4; ++i) {
        int gm = m0 + wm * 64 + i * 16 + q * 4;
#pragma unroll
        for (int j = 0; j < 4; ++j) {
            int gn = n0 + wn * 64 + j * 16 + lm;
#pragma unroll
            for (int r = 0; r < 4; ++r)
                Cw[(size_t)(gm + r) * NPIX + gn] = __float2bfloat16(acc[i][j][r]);
        }
    }
}

// ---------------- sigma_raw (conv rows of H, summed halves) + BN stats ----------------
__global__ void sigma_stats(const __hip_bfloat16* __restrict__ H0, const __hip_bfloat16* __restrict__ H1,
                            float* __restrict__ sraw, float* __restrict__ stats, int split) {
    int b = blockIdx.x;           // (n*9 + l)*4 + quarter
    int qq = b & 3, nl = b >> 2;
    int n = nl / 9, l = nl - n * 9;
    int t = threadIdx.x;
    int pix = qq * 256 + t;
    int y = pix >> 5, x = pix & 31;
    float v = 0.f;
#pragma unroll
    for (int k = 0; k < 9; ++k) {
        int yy = y + k / 3 - 1, xx = x + (k % 3) - 1;
        if (yy >= 0 && yy < 32 && xx >= 0 && xx < 32) {
            size_t idx = (size_t)(2304 + k * 9 + l) * NPIX + n * HW + yy * 32 + xx;
            float h = __bfloat162float(H0[idx]);
            if (split) h += __bfloat162float(H1[idx]);
            v += h;
        }
    }
    sraw[(size_t)nl * HW + pix] = v;
    __shared__ float r1[256], r2[256];
    r1[t] = v; r2[t] = v * v;
    __syncthreads();
    for (int s = 128; s > 0; s >>= 1) {
        if (t < s) { r1[t] += r1[t + s]; r2[t] += r2[t + s]; }
        __syncthreads();
    }
    if (t == 0) { atomicAdd(&stats[l], r1[0]); atomicAdd(&stats[9 + l], r2[0]); }
}

// ---------------- tail: BN + softmax (registers) + dynamic projection, 2 o per block ----------------
__global__ void tail(const __hip_bfloat16* __restrict__ H0, const __hip_bfloat16* __restrict__ H1,
                     const float* __restrict__ sraw, const float* __restrict__ stats,
                     const float* __restrict__ gamma, const float* __restrict__ beta,
                     float* __restrict__ out, int split) {
    int b = blockIdx.x;           // n*128 + og   (og -> o = og*2, og*2+1)
    int n = b >> 7, og = b & 127;
    int t = threadIdx.x;
    float mean[9], istd[9], gg[9], bb[9];
#pragma unroll
    for (int l = 0; l < 9; ++l) {
        float m = stats[l] * (1.f / 4096.f);
        float var = stats[9 + l] * (1.f / 4096.f) - m * m;
        mean[l] = m; istd[l] = rsqrtf(var + BN_EPS);
        gg[l] = gamma[l]; bb[l] = beta[l];
    }
    for (int i = 0; i < 4; ++i) {
        int pix = t + i * 256;
        int y = pix >> 5, x = pix & 31;
        float v[9];
        float mx = -1e30f;
#pragma unroll
        for (int l = 0; l < 9; ++l) {
            float tv = (sraw[(size_t)(n * 9 + l) * HW + pix] - mean[l]) * istd[l];
            tv = tv * gg[l] + bb[l];
            v[l] = tv; mx = fmaxf(mx, tv);
        }
        float ssum = 0.f;
#pragma unroll
        for (int l = 0; l < 9; ++l) { v[l] = __expf(v[l] - mx); ssum += v[l]; }
        float inv = 1.f / ssum;
        float sv[9]; int sp[9];
#pragma unroll
        for (int l = 0; l < 9; ++l) {
            int dy = l / 3 - 1, dx = l % 3 - 1;
            int yy = y + dy, xx = x + dx;
            bool ok = (yy >= 0 && yy < 32 && xx >= 0 && xx < 32);
            sp[l] = ok ? (pix + dy * 32 + dx) : pix;
            sv[l] = ok ? v[l] * inv : 0.f;
        }
#pragma unroll
        for (int oj = 0; oj < 2; ++oj) {
            int o = og * 2 + oj;
            float acc = 0.f;
#pragma unroll
            for (int l = 0; l < 9; ++l) {
                size_t idx = (size_t)(l * 256 + o) * NPIX + n * HW + sp[l];
                float h = __bfloat162float(H0[idx]);
                if (split) h += __bfloat162float(H1[idx]);
                acc += sv[l] * h;
            }
            out[((size_t)n * 256 + o) * HW + pix] = acc;
        }
    }
}

extern "C" void kernel_launch(void* const* d_in, const int* in_sizes, int n_in,
                              void* d_out, int out_size, void* d_ws, size_t ws_size,
                              hipStream_t stream) {
    const float* x     = (const float*)d_in[0];
    const float* cw    = (const float*)d_in[1];
    const float* gamma = (const float*)d_in[2];
    const float* beta  = (const float*)d_in[3];
    const float* wgt   = (const float*)d_in[4];

    char* ws = (char*)d_ws;
    u16* Abuf = (u16*)(ws);
    u16* XT   = (u16*)(ws + SZ_A);
    u16* H0   = (u16*)(ws + SZ_A + SZ_XT);

    // split-K x2 needs: A + XT + 2*H + sraw + stats
    size_t need_split = SZ_A + SZ_XT + 2 * SZ_H + SZ_SRAW + 256;
    int split = (ws_size >= need_split) ? 1 : 0;
    u16*   H1    = split ? (u16*)(ws + SZ_A + SZ_XT + SZ_H) : H0;
    char*  rest  = ws + SZ_A + SZ_XT + (split ? 2 : 1) * SZ_H;
    float* sraw  = (float*)rest;
    float* stats = (float*)(rest + SZ_SRAW);

    build_all<<<2314, 256, 0, stream>>>(x, wgt, cw, XT, Abuf, stats);
    gemm_bt<<<split ? 1216 : 608, 256, 0, stream>>>(Abuf, XT, (__hip_bfloat16*)H0, split);
    sigma_stats<<<N_IMG * KK * 4, 256, 0, stream>>>((const __hip_bfloat16*)H0, (const __hip_bfloat16*)H1,
                                                    sraw, stats, split);
    tail<<<N_IMG * 128, 256, 0, stream>>>((const __hip_bfloat16*)H0, (const __hip_bfloat16*)H1,
                                          sraw, stats, gamma, beta, (float*)d_out, split);
}

// Round 9
// 175.859 us; speedup vs baseline: 1.1938x; 1.1938x over previous
//
#include <hip/hip_runtime.h>
#include <hip/hip_bf16.h>
#include <stdint.h>

typedef unsigned short u16;
typedef __attribute__((ext_vector_type(8))) short short8;
typedef __attribute__((ext_vector_type(4))) float floatx4;

#define N_IMG 4
#define C_IN  2048
#define HW    1024
#define KK    9
#define O_OUT 256
#define NPIX  4096          // N_IMG*HW
#define M_PAD  2432         // 19*128 (2304 proj rows + 81 conv + pad)
#define K_DIM  2048
#define BN_EPS 1e-5f

// workspace offsets (bytes), 256-aligned (R7 layout)
#define OFF_A    0u
#define OFF_XT   9961472u          // A: 2432*2048*2
#define OFF_H    26738688u         // XT: 4096*2048*2
#define OFF_SRAW 46661632u         // H: 2432*4096*2
#define OFF_STAT 46809088u         // sraw: 36864*4

// fp32 -> bf16 bits, round-to-nearest-even
__device__ __forceinline__ u16 f2b(float f) {
    unsigned u = __float_as_uint(f);
    return (u16)((u + 0x7FFFu + ((u >> 16) & 1u)) >> 16);
}

__device__ __forceinline__ void load8f(const float* base, size_t eidx, u16* out) {
    const float* p = base + eidx;
    float4 a = ((const float4*)p)[0];
    float4 b = ((const float4*)p)[1];
    float f[8] = {a.x, a.y, a.z, a.w, b.x, b.y, b.z, b.w};
#pragma unroll
    for (int j = 0; j < 8; ++j) out[j] = f2b(f[j]);
}

// ---------------- merged staging kernel (R7-validated) ----------------
__global__ void build_all(const float* __restrict__ x, const float* __restrict__ wgt,
                          const float* __restrict__ cw, u16* __restrict__ xt,
                          u16* __restrict__ A, float* __restrict__ stats) {
    __shared__ __align__(16) u16 lds[9 * 2056];
    int b = blockIdx.x, t = threadIdx.x;
    if (b < 2048) {
        int c0 = (b & 31) * 64, p0 = ((b >> 5) & 15) * 64, n = b >> 9;
        int r = t >> 3, pv = (t & 7) * 8;
        u16 h0[8], h1[8];
        load8f(x, (size_t)(n * C_IN + c0 + r) * HW + p0 + pv, h0);
        load8f(x, (size_t)(n * C_IN + c0 + r + 32) * HW + p0 + pv, h1);
#pragma unroll
        for (int j = 0; j < 8; ++j) {
            lds[(pv + j) * 72 + r]      = h0[j];
            lds[(pv + j) * 72 + r + 32] = h1[j];
        }
        __syncthreads();
        int pr = t >> 3, cv = (t & 7) * 8;
        uint4 o0 = *(const uint4*)&lds[pr * 72 + cv];
        uint4 o1 = *(const uint4*)&lds[(pr + 32) * 72 + cv];
        *(uint4*)(xt + (size_t)(n * HW + p0 + pr) * K_DIM + c0 + cv) = o0;
        *(uint4*)(xt + (size_t)(n * HW + p0 + pr + 32) * K_DIM + c0 + cv) = o1;
    } else if (b < 2304) {
        int o = b - 2048;
        size_t base = (size_t)o * 18432;   // weight[o][c][l], e = c*9+l
        for (int i = 0; i < 9; ++i) {
            int e0 = (t + i * 256) * 8;
            u16 hv[8];
            load8f(wgt, base + e0, hv);
#pragma unroll
            for (int j = 0; j < 8; ++j) {
                int e = e0 + j;
                int c = e / 9, l = e - c * 9;
                lds[l * 2056 + c] = hv[j];
            }
        }
        __syncthreads();
        for (int l = 0; l < 9; ++l) {
            size_t row = (size_t)l * 256 + o;
            *(uint4*)(A + row * K_DIM + t * 8) = *(const uint4*)&lds[l * 2056 + t * 8];
        }
    } else if (b < 2313) {
        int l = b - 2304;
        size_t base = (size_t)l * 18432;    // conv_w[l][c][k], e = c*9+k
        for (int i = 0; i < 9; ++i) {
            int e0 = (t + i * 256) * 8;
            u16 hv[8];
            load8f(cw, base + e0, hv);
#pragma unroll
            for (int j = 0; j < 8; ++j) {
                int e = e0 + j;
                int c = e / 9, k = e - c * 9;
                lds[k * 2056 + c] = hv[j];
            }
        }
        __syncthreads();
        for (int k = 0; k < 9; ++k) {
            size_t row = 2304 + (size_t)k * 9 + l;
            *(uint4*)(A + row * K_DIM + t * 8) = *(const uint4*)&lds[k * 2056 + t * 8];
        }
    } else {
        uint4 z = {0, 0, 0, 0};
        uint4* dst = (uint4*)(A + (size_t)2385 * K_DIM);
        for (int i = t; i < (47 * 2048) / 8; i += 256) dst[i] = z;
        if (t < 18) stats[t] = 0.0f;
    }
}

// ---------------- GEMM: H = A * XT^T, 128x128 tiles, BK=64 (2 k-steps per barrier) ----------------
__device__ __forceinline__ void gload_lds16(const void* g, void* l) {
    __builtin_amdgcn_global_load_lds((__attribute__((address_space(1))) void*)(g),
                                     (__attribute__((address_space(3))) void*)(l), 16, 0, 0);
}

__global__ void gemm_bt(const u16* __restrict__ A, const u16* __restrict__ B,
                        __hip_bfloat16* __restrict__ C) {
    // layout: [ks in 0..1][chunk 0..7][16 rows][32 k]; chunk = 512 u16, ks-half = 4096 u16
    __shared__ __align__(16) u16 As[2 * 128 * 32];
    __shared__ __align__(16) u16 Bs[2 * 128 * 32];
    int bx = blockIdx.x;
    int mt = bx % 19, nt = bx / 19;
    int m0 = mt * 128, n0 = nt * 128;
    int t = threadIdx.x;
    int w = t >> 6, lam = t & 63;
    int wm = w >> 1, wn = w & 1;
    int lm = lam & 15, q = lam >> 4;

    floatx4 acc[4][4];
    floatx4 z = {0.f, 0.f, 0.f, 0.f};
#pragma unroll
    for (int i = 0; i < 4; ++i)
#pragma unroll
        for (int j = 0; j < 4; ++j) acc[i][j] = z;

    int rsub = lam >> 2;            // 0..15
    int kc = (lam & 3) * 8;         // 0,8,16,24
    const u16* gA[4]; const u16* gB[4];
    u16* lA[4];       u16* lB[4];
#pragma unroll
    for (int ii = 0; ii < 4; ++ii) {
        int c = w * 4 + ii;         // 0..15
        int rc = c & 7, ks = c >> 3;
        gA[ii] = A + (size_t)(m0 + rc * 16 + rsub) * K_DIM + ks * 32 + kc;
        gB[ii] = B + (size_t)(n0 + rc * 16 + rsub) * K_DIM + ks * 32 + kc;
        lA[ii] = As + ks * 4096 + rc * 512;
        lB[ii] = Bs + ks * 4096 + rc * 512;
    }

    for (int kt = 0; kt < K_DIM / 64; ++kt) {
#pragma unroll
        for (int ii = 0; ii < 4; ++ii) {
            gload_lds16(gA[ii], lA[ii]);
            gload_lds16(gB[ii], lB[ii]);
            gA[ii] += 64; gB[ii] += 64;
        }
        __syncthreads();
#pragma unroll
        for (int ks = 0; ks < 2; ++ks) {
            short8 af[4], bf[4];
#pragma unroll
            for (int i = 0; i < 4; ++i)
                af[i] = *(const short8*)(As + ks * 4096 + (wm * 64 + i * 16 + lm) * 32 + q * 8);
#pragma unroll
            for (int j = 0; j < 4; ++j)
                bf[j] = *(const short8*)(Bs + ks * 4096 + (wn * 64 + j * 16 + lm) * 32 + q * 8);
#pragma unroll
            for (int i = 0; i < 4; ++i)
#pragma unroll
                for (int j = 0; j < 4; ++j)
                    acc[i][j] = __builtin_amdgcn_mfma_f32_16x16x32_bf16(af[i], bf[j], acc[i][j], 0, 0, 0);
        }
        __syncthreads();
    }
    // C/D layout: col=lane&15, row=(lane>>4)*4+reg
#pragma unroll
    for (int i = 0; i < 4; ++i) {
        int gm = m0 + wm * 64 + i * 16 + q * 4;
#pragma unroll
        for (int j = 0; j < 4; ++j) {
            int gn = n0 + wn * 64 + j * 16 + lm;
#pragma unroll
            for (int r = 0; r < 4; ++r)
                C[(size_t)(gm + r) * NPIX + gn] = __float2bfloat16(acc[i][j][r]);
        }
    }
}

// ---------------- sigma_raw (conv rows of H) + BN stats (R7-validated) ----------------
__global__ void sigma_stats(const __hip_bfloat16* __restrict__ Hm, float* __restrict__ sraw,
                            float* __restrict__ stats) {
    int b = blockIdx.x;           // (n*9 + l)*4 + quarter
    int qq = b & 3, nl = b >> 2;
    int n = nl / 9, l = nl - n * 9;
    int t = threadIdx.x;
    int pix = qq * 256 + t;
    int y = pix >> 5, x = pix & 31;
    float v = 0.f;
#pragma unroll
    for (int k = 0; k < 9; ++k) {
        int yy = y + k / 3 - 1, xx = x + (k % 3) - 1;
        if (yy >= 0 && yy < 32 && xx >= 0 && xx < 32)
            v += __bfloat162float(Hm[(size_t)(2304 + k * 9 + l) * NPIX + n * HW + yy * 32 + xx]);
    }
    sraw[(size_t)nl * HW + pix] = v;
    __shared__ float r1[256], r2[256];
    r1[t] = v; r2[t] = v * v;
    __syncthreads();
    for (int s = 128; s > 0; s >>= 1) {
        if (t < s) { r1[t] += r1[t + s]; r2[t] += r2[t + s]; }
        __syncthreads();
    }
    if (t == 0) { atomicAdd(&stats[l], r1[0]); atomicAdd(&stats[9 + l], r2[0]); }
}

// ---------------- tail: BN + softmax (register recompute) + dynamic projection (R7-validated) ----------------
__global__ void tail(const __hip_bfloat16* __restrict__ Hm, const float* __restrict__ sraw,
                     const float* __restrict__ stats, const float* __restrict__ gamma,
                     const float* __restrict__ beta, float* __restrict__ out) {
    int b = blockIdx.x;
    int n = b >> 8, o = b & 255;
    int t = threadIdx.x;
    float mean[9], istd[9], gg[9], bb[9];
#pragma unroll
    for (int l = 0; l < 9; ++l) {
        float m = stats[l] * (1.f / 4096.f);
        float var = stats[9 + l] * (1.f / 4096.f) - m * m;
        mean[l] = m; istd[l] = rsqrtf(var + BN_EPS);
        gg[l] = gamma[l]; bb[l] = beta[l];
    }
    for (int i = 0; i < 4; ++i) {
        int pix = t + i * 256;
        int y = pix >> 5, x = pix & 31;
        float v[9];
        float mx = -1e30f;
#pragma unroll
        for (int l = 0; l < 9; ++l) {
            float tv = (sraw[(size_t)(n * 9 + l) * HW + pix] - mean[l]) * istd[l];
            tv = tv * gg[l] + bb[l];
            v[l] = tv; mx = fmaxf(mx, tv);
        }
        float ssum = 0.f;
#pragma unroll
        for (int l = 0; l < 9; ++l) { v[l] = __expf(v[l] - mx); ssum += v[l]; }
        float inv = 1.f / ssum;
        float acc = 0.f;
#pragma unroll
        for (int l = 0; l < 9; ++l) {
            int dy = l / 3 - 1, dx = l % 3 - 1;
            int yy = y + dy, xx = x + dx;
            if (yy >= 0 && yy < 32 && xx >= 0 && xx < 32) {
                float h = __bfloat162float(Hm[(size_t)(l * 256 + o) * NPIX + n * HW + yy * 32 + xx]);
                acc += v[l] * inv * h;
            }
        }
        out[((size_t)n * 256 + o) * HW + pix] = acc;
    }
}

extern "C" void kernel_launch(void* const* d_in, const int* in_sizes, int n_in,
                              void* d_out, int out_size, void* d_ws, size_t ws_size,
                              hipStream_t stream) {
    const float* x     = (const float*)d_in[0];
    const float* cw    = (const float*)d_in[1];
    const float* gamma = (const float*)d_in[2];
    const float* beta  = (const float*)d_in[3];
    const float* wgt   = (const float*)d_in[4];

    char* ws = (char*)d_ws;
    u16*   Abuf = (u16*)(ws + OFF_A);
    u16*   XT   = (u16*)(ws + OFF_XT);
    u16*   Hm   = (u16*)(ws + OFF_H);
    float* sraw = (float*)(ws + OFF_SRAW);
    float* stats= (float*)(ws + OFF_STAT);

    build_all<<<2314, 256, 0, stream>>>(x, wgt, cw, XT, Abuf, stats);
    gemm_bt<<<19 * 32, 256, 0, stream>>>(Abuf, XT, (__hip_bfloat16*)Hm);
    sigma_stats<<<N_IMG * KK * 4, 256, 0, stream>>>((const __hip_bfloat16*)Hm, sraw, stats);
    tail<<<N_IMG * O_OUT, 256, 0, stream>>>((const __hip_bfloat16*)Hm, sraw, stats, gamma, beta, (float*)d_out);
}

// Round 10
// 171.954 us; speedup vs baseline: 1.2209x; 1.0227x over previous
//
#include <hip/hip_runtime.h>
#include <hip/hip_bf16.h>
#include <stdint.h>

typedef unsigned short u16;
typedef __attribute__((ext_vector_type(8))) short short8;
typedef __attribute__((ext_vector_type(4))) float floatx4;

#define N_IMG 4
#define C_IN  2048
#define HW    1024
#define KK    9
#define O_OUT 256
#define NPIX  4096          // N_IMG*HW
#define M_PAD  2432         // 19*128 (2304 proj rows + 81 conv + pad)
#define K_DIM  2048
#define BN_EPS 1e-5f

// workspace offsets (bytes), 256-aligned
#define OFF_A    0u
#define OFF_XT   9961472u          // A: 2432*2048*2
#define OFF_H    26738688u         // XT: 4096*2048*2
#define OFF_SRAW 46661632u         // H: 2432*4096*2
#define OFF_STAT 46809088u         // sraw: 36864*4

// fp32 -> bf16 bits, round-to-nearest-even
__device__ __forceinline__ u16 f2b(float f) {
    unsigned u = __float_as_uint(f);
    return (u16)((u + 0x7FFFu + ((u >> 16) & 1u)) >> 16);
}

__device__ __forceinline__ void load8f(const float* base, size_t eidx, u16* out) {
    const float* p = base + eidx;
    float4 a = ((const float4*)p)[0];
    float4 b = ((const float4*)p)[1];
    float f[8] = {a.x, a.y, a.z, a.w, b.x, b.y, b.z, b.w};
#pragma unroll
    for (int j = 0; j < 8; ++j) out[j] = f2b(f[j]);
}

// ---------------- merged staging kernel ----------------
// blocks [0,2048): transpose x -> XT via u32-packed LDS (<=2-way bank conflicts; validated R8)
// blocks [2048,2304): A proj rows; [2304,2313): A conv rows; 2313: zero-pad + stats
__global__ void build_all(const float* __restrict__ x, const float* __restrict__ wgt,
                          const float* __restrict__ cw, u16* __restrict__ xt,
                          u16* __restrict__ A, float* __restrict__ stats) {
    __shared__ __align__(16) u16 lds[9 * 2056];
    int b = blockIdx.x, t = threadIdx.x;
    if (b < 2048) {
        int c0 = (b & 31) * 64, p0 = ((b >> 5) & 15) * 64, n = b >> 9;
        int rp = t >> 3;                // channel-pair 0..31
        int pv = (t & 7) * 8;           // pixel group
        u16 h0[8], h1[8];
        load8f(x, (size_t)(n * C_IN + c0 + 2 * rp) * HW + p0 + pv, h0);
        load8f(x, (size_t)(n * C_IN + c0 + 2 * rp + 1) * HW + p0 + pv, h1);
        unsigned* l32 = (unsigned*)lds;   // [64 pixels][stride 35 u32]
#pragma unroll
        for (int j = 0; j < 8; ++j)
            l32[(pv + j) * 35 + rp] = (unsigned)h0[j] | ((unsigned)h1[j] << 16);
        __syncthreads();
        int pr = t >> 3, cq = (t & 7) * 4;   // pixel, u32-quad (8 channels)
        unsigned o0[4], o1[4];
#pragma unroll
        for (int i = 0; i < 4; ++i) {
            o0[i] = l32[pr * 35 + cq + i];
            o1[i] = l32[(pr + 32) * 35 + cq + i];
        }
        *(uint4*)(xt + (size_t)(n * HW + p0 + pr) * K_DIM + c0 + cq * 2) = *(uint4*)o0;
        *(uint4*)(xt + (size_t)(n * HW + p0 + pr + 32) * K_DIM + c0 + cq * 2) = *(uint4*)o1;
    } else if (b < 2304) {
        int o = b - 2048;
        size_t base = (size_t)o * 18432;   // weight[o][c][l], e = c*9+l
        for (int i = 0; i < 9; ++i) {
            int e0 = (t + i * 256) * 8;
            u16 hv[8];
            load8f(wgt, base + e0, hv);
#pragma unroll
            for (int j = 0; j < 8; ++j) {
                int e = e0 + j;
                int c = e / 9, l = e - c * 9;
                lds[l * 2056 + c] = hv[j];
            }
        }
        __syncthreads();
        for (int l = 0; l < 9; ++l) {
            size_t row = (size_t)l * 256 + o;
            *(uint4*)(A + row * K_DIM + t * 8) = *(const uint4*)&lds[l * 2056 + t * 8];
        }
    } else if (b < 2313) {
        int l = b - 2304;
        size_t base = (size_t)l * 18432;    // conv_w[l][c][k], e = c*9+k
        for (int i = 0; i < 9; ++i) {
            int e0 = (t + i * 256) * 8;
            u16 hv[8];
            load8f(cw, base + e0, hv);
#pragma unroll
            for (int j = 0; j < 8; ++j) {
                int e = e0 + j;
                int c = e / 9, k = e - c * 9;
                lds[k * 2056 + c] = hv[j];
            }
        }
        __syncthreads();
        for (int k = 0; k < 9; ++k) {
            size_t row = 2304 + (size_t)k * 9 + l;
            *(uint4*)(A + row * K_DIM + t * 8) = *(const uint4*)&lds[k * 2056 + t * 8];
        }
    } else {
        uint4 z = {0, 0, 0, 0};
        uint4* dst = (uint4*)(A + (size_t)2385 * K_DIM);
        for (int i = t; i < (47 * 2048) / 8; i += 256) dst[i] = z;
        if (t < 18) stats[t] = 0.0f;
    }
}

// ---------------- GEMM: H = A * XT^T, 128x128 tiles, BK=64 (R9-validated) ----------------
__device__ __forceinline__ void gload_lds16(const void* g, void* l) {
    __builtin_amdgcn_global_load_lds((__attribute__((address_space(1))) void*)(g),
                                     (__attribute__((address_space(3))) void*)(l), 16, 0, 0);
}

__global__ void gemm_bt(const u16* __restrict__ A, const u16* __restrict__ B,
                        __hip_bfloat16* __restrict__ C) {
    __shared__ __align__(16) u16 As[2 * 128 * 32];
    __shared__ __align__(16) u16 Bs[2 * 128 * 32];
    int bx = blockIdx.x;
    int mt = bx % 19, nt = bx / 19;
    int m0 = mt * 128, n0 = nt * 128;
    int t = threadIdx.x;
    int w = t >> 6, lam = t & 63;
    int wm = w >> 1, wn = w & 1;
    int lm = lam & 15, q = lam >> 4;

    floatx4 acc[4][4];
    floatx4 z = {0.f, 0.f, 0.f, 0.f};
#pragma unroll
    for (int i = 0; i < 4; ++i)
#pragma unroll
        for (int j = 0; j < 4; ++j) acc[i][j] = z;

    int rsub = lam >> 2;            // 0..15
    int kc = (lam & 3) * 8;         // 0,8,16,24
    const u16* gA[4]; const u16* gB[4];
    u16* lA[4];       u16* lB[4];
#pragma unroll
    for (int ii = 0; ii < 4; ++ii) {
        int c = w * 4 + ii;         // 0..15
        int rc = c & 7, ks = c >> 3;
        gA[ii] = A + (size_t)(m0 + rc * 16 + rsub) * K_DIM + ks * 32 + kc;
        gB[ii] = B + (size_t)(n0 + rc * 16 + rsub) * K_DIM + ks * 32 + kc;
        lA[ii] = As + ks * 4096 + rc * 512;
        lB[ii] = Bs + ks * 4096 + rc * 512;
    }

    for (int kt = 0; kt < K_DIM / 64; ++kt) {
#pragma unroll
        for (int ii = 0; ii < 4; ++ii) {
            gload_lds16(gA[ii], lA[ii]);
            gload_lds16(gB[ii], lB[ii]);
            gA[ii] += 64; gB[ii] += 64;
        }
        __syncthreads();
#pragma unroll
        for (int ks = 0; ks < 2; ++ks) {
            short8 af[4], bf[4];
#pragma unroll
            for (int i = 0; i < 4; ++i)
                af[i] = *(const short8*)(As + ks * 4096 + (wm * 64 + i * 16 + lm) * 32 + q * 8);
#pragma unroll
            for (int j = 0; j < 4; ++j)
                bf[j] = *(const short8*)(Bs + ks * 4096 + (wn * 64 + j * 16 + lm) * 32 + q * 8);
#pragma unroll
            for (int i = 0; i < 4; ++i)
#pragma unroll
                for (int j = 0; j < 4; ++j)
                    acc[i][j] = __builtin_amdgcn_mfma_f32_16x16x32_bf16(af[i], bf[j], acc[i][j], 0, 0, 0);
        }
        __syncthreads();
    }
    // C/D layout: col=lane&15, row=(lane>>4)*4+reg
#pragma unroll
    for (int i = 0; i < 4; ++i) {
        int gm = m0 + wm * 64 + i * 16 + q * 4;
#pragma unroll
        for (int j = 0; j < 4; ++j) {
            int gn = n0 + wn * 64 + j * 16 + lm;
#pragma unroll
            for (int r = 0; r < 4; ++r)
                C[(size_t)(gm + r) * NPIX + gn] = __float2bfloat16(acc[i][j][r]);
        }
    }
}

// ---------------- sigma_raw (conv rows of H) + BN stats (R7-validated) ----------------
__global__ void sigma_stats(const __hip_bfloat16* __restrict__ Hm, float* __restrict__ sraw,
                            float* __restrict__ stats) {
    int b = blockIdx.x;           // (n*9 + l)*4 + quarter
    int qq = b & 3, nl = b >> 2;
    int n = nl / 9, l = nl - n * 9;
    int t = threadIdx.x;
    int pix = qq * 256 + t;
    int y = pix >> 5, x = pix & 31;
    float v = 0.f;
#pragma unroll
    for (int k = 0; k < 9; ++k) {
        int yy = y + k / 3 - 1, xx = x + (k % 3) - 1;
        if (yy >= 0 && yy < 32 && xx >= 0 && xx < 32)
            v += __bfloat162float(Hm[(size_t)(2304 + k * 9 + l) * NPIX + n * HW + yy * 32 + xx]);
    }
    sraw[(size_t)nl * HW + pix] = v;
    __shared__ float r1[256], r2[256];
    r1[t] = v; r2[t] = v * v;
    __syncthreads();
    for (int s = 128; s > 0; s >>= 1) {
        if (t < s) { r1[t] += r1[t + s]; r2[t] += r2[t + s]; }
        __syncthreads();
    }
    if (t == 0) { atomicAdd(&stats[l], r1[0]); atomicAdd(&stats[9 + l], r2[0]); }
}

// ---------------- tail: BN + softmax + projection; 2 o per block, 4 consecutive pix/thread ----------------
// grid 512: b = n*128 + og; o = 2*og, 2*og+1. Thread t: pixels 4t..4t+3 (same image row since 4|32).
__global__ void tail(const __hip_bfloat16* __restrict__ Hm, const float* __restrict__ sraw,
                     const float* __restrict__ stats, const float* __restrict__ gamma,
                     const float* __restrict__ beta, float* __restrict__ out) {
    int b = blockIdx.x;
    int n = b >> 7, og = b & 127;
    int t = threadIdx.x;
    float mean[9], istd[9], gg[9], bb[9];
#pragma unroll
    for (int l = 0; l < 9; ++l) {
        float m = stats[l] * (1.f / 4096.f);
        float var = stats[9 + l] * (1.f / 4096.f) - m * m;
        mean[l] = m; istd[l] = rsqrtf(var + BN_EPS);
        gg[l] = gamma[l]; bb[l] = beta[l];
    }
    int pix0 = t * 4;
    int y = pix0 >> 5, x0 = pix0 & 31;
    float sr[9][4];
#pragma unroll
    for (int l = 0; l < 9; ++l)
        *(float4*)sr[l] = *(const float4*)&sraw[(size_t)(n * 9 + l) * HW + pix0];

    float acc0[4], acc1[4];
#pragma unroll
    for (int j = 0; j < 4; ++j) { acc0[j] = 0.f; acc1[j] = 0.f; }

    const __hip_bfloat16* hb = Hm + (size_t)n * HW;
    size_t obase = (size_t)(og * 2) * NPIX;

#pragma unroll
    for (int j = 0; j < 4; ++j) {
        int x = x0 + j;
        float v[9];
        float mx = -1e30f;
#pragma unroll
        for (int l = 0; l < 9; ++l) {
            float tv = (sr[l][j] - mean[l]) * istd[l];
            tv = tv * gg[l] + bb[l];
            v[l] = tv; mx = fmaxf(mx, tv);
        }
        float ssum = 0.f;
#pragma unroll
        for (int l = 0; l < 9; ++l) { v[l] = __expf(v[l] - mx); ssum += v[l]; }
        float inv = 1.f / ssum;
#pragma unroll
        for (int l = 0; l < 9; ++l) {
            int dy = l / 3 - 1, dx = l % 3 - 1;
            int yy = y + dy, xx = x + dx;
            if (yy >= 0 && yy < 32 && xx >= 0 && xx < 32) {
                float sv = v[l] * inv;
                size_t hidx = (size_t)l * 256 * NPIX + obase + (size_t)(pix0 + j + dy * 32 + dx);
                acc0[j] += sv * __bfloat162float(hb[hidx]);
                acc1[j] += sv * __bfloat162float(hb[hidx + NPIX]);
            }
        }
    }
    float* ob = out + ((size_t)n * 256 + og * 2) * HW + pix0;
    *(float4*)ob = *(float4*)acc0;
    *(float4*)(ob + HW) = *(float4*)acc1;
}

extern "C" void kernel_launch(void* const* d_in, const int* in_sizes, int n_in,
                              void* d_out, int out_size, void* d_ws, size_t ws_size,
                              hipStream_t stream) {
    const float* x     = (const float*)d_in[0];
    const float* cw    = (const float*)d_in[1];
    const float* gamma = (const float*)d_in[2];
    const float* beta  = (const float*)d_in[3];
    const float* wgt   = (const float*)d_in[4];

    char* ws = (char*)d_ws;
    u16*   Abuf = (u16*)(ws + OFF_A);
    u16*   XT   = (u16*)(ws + OFF_XT);
    u16*   Hm   = (u16*)(ws + OFF_H);
    float* sraw = (float*)(ws + OFF_SRAW);
    float* stats= (float*)(ws + OFF_STAT);

    build_all<<<2314, 256, 0, stream>>>(x, wgt, cw, XT, Abuf, stats);
    gemm_bt<<<19 * 32, 256, 0, stream>>>(Abuf, XT, (__hip_bfloat16*)Hm);
    sigma_stats<<<N_IMG * KK * 4, 256, 0, stream>>>((const __hip_bfloat16*)Hm, sraw, stats);
    tail<<<512, 256, 0, stream>>>((const __hip_bfloat16*)Hm, sraw, stats, gamma, beta, (float*)d_out);
}

// Round 11
// 169.440 us; speedup vs baseline: 1.2390x; 1.0148x over previous
//
#include <hip/hip_runtime.h>
#include <hip/hip_bf16.h>
#include <stdint.h>

typedef unsigned short u16;
typedef __attribute__((ext_vector_type(8))) short short8;
typedef __attribute__((ext_vector_type(4))) float floatx4;

#define N_IMG 4
#define C_IN  2048
#define HW    1024
#define KK    9
#define O_OUT 256
#define NPIX  4096          // N_IMG*HW
#define M_PAD  2432         // 19*128 (2304 proj rows + 81 conv + pad)
#define K_DIM  2048
#define BN_EPS 1e-5f

// workspace offsets (bytes), 256-aligned
#define OFF_A    0u
#define OFF_XT   9961472u          // A: 2432*2048*2
#define OFF_H    26738688u         // XT: 4096*2048*2
#define OFF_SRAW 46661632u         // H: 2432*4096*2
#define OFF_STAT 46809088u         // sraw: 36864*4

// fp32 -> bf16 bits, round-to-nearest-even
__device__ __forceinline__ u16 f2b(float f) {
    unsigned u = __float_as_uint(f);
    return (u16)((u + 0x7FFFu + ((u >> 16) & 1u)) >> 16);
}

__device__ __forceinline__ void load8f(const float* base, size_t eidx, u16* out) {
    const float* p = base + eidx;
    float4 a = ((const float4*)p)[0];
    float4 b = ((const float4*)p)[1];
    float f[8] = {a.x, a.y, a.z, a.w, b.x, b.y, b.z, b.w};
#pragma unroll
    for (int j = 0; j < 8; ++j) out[j] = f2b(f[j]);
}

// ---------------- merged staging kernel (R10-validated) ----------------
__global__ void build_all(const float* __restrict__ x, const float* __restrict__ wgt,
                          const float* __restrict__ cw, u16* __restrict__ xt,
                          u16* __restrict__ A, float* __restrict__ stats) {
    __shared__ __align__(16) u16 lds[9 * 2056];
    int b = blockIdx.x, t = threadIdx.x;
    if (b < 2048) {
        int c0 = (b & 31) * 64, p0 = ((b >> 5) & 15) * 64, n = b >> 9;
        int rp = t >> 3;                // channel-pair 0..31
        int pv = (t & 7) * 8;           // pixel group
        u16 h0[8], h1[8];
        load8f(x, (size_t)(n * C_IN + c0 + 2 * rp) * HW + p0 + pv, h0);
        load8f(x, (size_t)(n * C_IN + c0 + 2 * rp + 1) * HW + p0 + pv, h1);
        unsigned* l32 = (unsigned*)lds;   // [64 pixels][stride 35 u32]
#pragma unroll
        for (int j = 0; j < 8; ++j)
            l32[(pv + j) * 35 + rp] = (unsigned)h0[j] | ((unsigned)h1[j] << 16);
        __syncthreads();
        int pr = t >> 3, cq = (t & 7) * 4;   // pixel, u32-quad (8 channels)
        unsigned o0[4], o1[4];
#pragma unroll
        for (int i = 0; i < 4; ++i) {
            o0[i] = l32[pr * 35 + cq + i];
            o1[i] = l32[(pr + 32) * 35 + cq + i];
        }
        *(uint4*)(xt + (size_t)(n * HW + p0 + pr) * K_DIM + c0 + cq * 2) = *(uint4*)o0;
        *(uint4*)(xt + (size_t)(n * HW + p0 + pr + 32) * K_DIM + c0 + cq * 2) = *(uint4*)o1;
    } else if (b < 2304) {
        int o = b - 2048;
        size_t base = (size_t)o * 18432;   // weight[o][c][l], e = c*9+l
        for (int i = 0; i < 9; ++i) {
            int e0 = (t + i * 256) * 8;
            u16 hv[8];
            load8f(wgt, base + e0, hv);
#pragma unroll
            for (int j = 0; j < 8; ++j) {
                int e = e0 + j;
                int c = e / 9, l = e - c * 9;
                lds[l * 2056 + c] = hv[j];
            }
        }
        __syncthreads();
        for (int l = 0; l < 9; ++l) {
            size_t row = (size_t)l * 256 + o;
            *(uint4*)(A + row * K_DIM + t * 8) = *(const uint4*)&lds[l * 2056 + t * 8];
        }
    } else if (b < 2313) {
        int l = b - 2304;
        size_t base = (size_t)l * 18432;    // conv_w[l][c][k], e = c*9+k
        for (int i = 0; i < 9; ++i) {
            int e0 = (t + i * 256) * 8;
            u16 hv[8];
            load8f(cw, base + e0, hv);
#pragma unroll
            for (int j = 0; j < 8; ++j) {
                int e = e0 + j;
                int c = e / 9, k = e - c * 9;
                lds[k * 2056 + c] = hv[j];
            }
        }
        __syncthreads();
        for (int k = 0; k < 9; ++k) {
            size_t row = 2304 + (size_t)k * 9 + l;
            *(uint4*)(A + row * K_DIM + t * 8) = *(const uint4*)&lds[k * 2056 + t * 8];
        }
    } else {
        uint4 z = {0, 0, 0, 0};
        uint4* dst = (uint4*)(A + (size_t)2385 * K_DIM);
        for (int i = t; i < (47 * 2048) / 8; i += 256) dst[i] = z;
        if (t < 18) stats[t] = 0.0f;
    }
}

// ---------------- GEMM: H = A * XT^T, 128x128 tiles, BK=64 (R9-validated) ----------------
__device__ __forceinline__ void gload_lds16(const void* g, void* l) {
    __builtin_amdgcn_global_load_lds((__attribute__((address_space(1))) void*)(g),
                                     (__attribute__((address_space(3))) void*)(l), 16, 0, 0);
}

__global__ void gemm_bt(const u16* __restrict__ A, const u16* __restrict__ B,
                        __hip_bfloat16* __restrict__ C) {
    __shared__ __align__(16) u16 As[2 * 128 * 32];
    __shared__ __align__(16) u16 Bs[2 * 128 * 32];
    int bx = blockIdx.x;
    int mt = bx % 19, nt = bx / 19;
    int m0 = mt * 128, n0 = nt * 128;
    int t = threadIdx.x;
    int w = t >> 6, lam = t & 63;
    int wm = w >> 1, wn = w & 1;
    int lm = lam & 15, q = lam >> 4;

    floatx4 acc[4][4];
    floatx4 z = {0.f, 0.f, 0.f, 0.f};
#pragma unroll
    for (int i = 0; i < 4; ++i)
#pragma unroll
        for (int j = 0; j < 4; ++j) acc[i][j] = z;

    int rsub = lam >> 2;            // 0..15
    int kc = (lam & 3) * 8;         // 0,8,16,24
    const u16* gA[4]; const u16* gB[4];
    u16* lA[4];       u16* lB[4];
#pragma unroll
    for (int ii = 0; ii < 4; ++ii) {
        int c = w * 4 + ii;         // 0..15
        int rc = c & 7, ks = c >> 3;
        gA[ii] = A + (size_t)(m0 + rc * 16 + rsub) * K_DIM + ks * 32 + kc;
        gB[ii] = B + (size_t)(n0 + rc * 16 + rsub) * K_DIM + ks * 32 + kc;
        lA[ii] = As + ks * 4096 + rc * 512;
        lB[ii] = Bs + ks * 4096 + rc * 512;
    }

    for (int kt = 0; kt < K_DIM / 64; ++kt) {
#pragma unroll
        for (int ii = 0; ii < 4; ++ii) {
            gload_lds16(gA[ii], lA[ii]);
            gload_lds16(gB[ii], lB[ii]);
            gA[ii] += 64; gB[ii] += 64;
        }
        __syncthreads();
#pragma unroll
        for (int ks = 0; ks < 2; ++ks) {
            short8 af[4], bf[4];
#pragma unroll
            for (int i = 0; i < 4; ++i)
                af[i] = *(const short8*)(As + ks * 4096 + (wm * 64 + i * 16 + lm) * 32 + q * 8);
#pragma unroll
            for (int j = 0; j < 4; ++j)
                bf[j] = *(const short8*)(Bs + ks * 4096 + (wn * 64 + j * 16 + lm) * 32 + q * 8);
#pragma unroll
            for (int i = 0; i < 4; ++i)
#pragma unroll
                for (int j = 0; j < 4; ++j)
                    acc[i][j] = __builtin_amdgcn_mfma_f32_16x16x32_bf16(af[i], bf[j], acc[i][j], 0, 0, 0);
        }
        __syncthreads();
    }
    // C/D layout: col=lane&15, row=(lane>>4)*4+reg
#pragma unroll
    for (int i = 0; i < 4; ++i) {
        int gm = m0 + wm * 64 + i * 16 + q * 4;
#pragma unroll
        for (int j = 0; j < 4; ++j) {
            int gn = n0 + wn * 64 + j * 16 + lm;
#pragma unroll
            for (int r = 0; r < 4; ++r)
                C[(size_t)(gm + r) * NPIX + gn] = __float2bfloat16(acc[i][j][r]);
        }
    }
}

// ---------------- sigma_raw (conv rows of H) + BN stats (R7-validated) ----------------
__global__ void sigma_stats(const __hip_bfloat16* __restrict__ Hm, float* __restrict__ sraw,
                            float* __restrict__ stats) {
    int b = blockIdx.x;           // (n*9 + l)*4 + quarter
    int qq = b & 3, nl = b >> 2;
    int n = nl / 9, l = nl - n * 9;
    int t = threadIdx.x;
    int pix = qq * 256 + t;
    int y = pix >> 5, x = pix & 31;
    float v = 0.f;
#pragma unroll
    for (int k = 0; k < 9; ++k) {
        int yy = y + k / 3 - 1, xx = x + (k % 3) - 1;
        if (yy >= 0 && yy < 32 && xx >= 0 && xx < 32)
            v += __bfloat162float(Hm[(size_t)(2304 + k * 9 + l) * NPIX + n * HW + yy * 32 + xx]);
    }
    sraw[(size_t)nl * HW + pix] = v;
    __shared__ float r1[256], r2[256];
    r1[t] = v; r2[t] = v * v;
    __syncthreads();
    for (int s = 128; s > 0; s >>= 1) {
        if (t < s) { r1[t] += r1[t + s]; r2[t] += r2[t + s]; }
        __syncthreads();
    }
    if (t == 0) { atomicAdd(&stats[l], r1[0]); atomicAdd(&stats[9 + l], r2[0]); }
}

// ---------------- tail v3: lane->consecutive pixel (coalesced H reads), 2 o per block, pixel-halves ----------------
// grid 1024: b = n*256 + ph*128 + og; channels o = 2*og,2*og+1; pixels ph*512 + i*256 + t (i=0,1)
__global__ void tail(const __hip_bfloat16* __restrict__ Hm, const float* __restrict__ sraw,
                     const float* __restrict__ stats, const float* __restrict__ gamma,
                     const float* __restrict__ beta, float* __restrict__ out) {
    int b = blockIdx.x;
    int n = b >> 8, rem = b & 255;
    int ph = rem >> 7, og = rem & 127;
    int t = threadIdx.x;
    float mean[9], istd[9], gg[9], bb[9];
#pragma unroll
    for (int l = 0; l < 9; ++l) {
        float m = stats[l] * (1.f / 4096.f);
        float var = stats[9 + l] * (1.f / 4096.f) - m * m;
        mean[l] = m; istd[l] = rsqrtf(var + BN_EPS);
        gg[l] = gamma[l]; bb[l] = beta[l];
    }
    const __hip_bfloat16* hb = Hm + (size_t)(og * 2) * NPIX + (size_t)n * HW;
    float* ob = out + ((size_t)n * 256 + og * 2) * HW;
#pragma unroll
    for (int i = 0; i < 2; ++i) {
        int pix = ph * 512 + i * 256 + t;
        int y = pix >> 5, x = pix & 31;
        float v[9];
        float mx = -1e30f;
#pragma unroll
        for (int l = 0; l < 9; ++l) {
            float tv = (sraw[(size_t)(n * 9 + l) * HW + pix] - mean[l]) * istd[l];
            tv = tv * gg[l] + bb[l];
            v[l] = tv; mx = fmaxf(mx, tv);
        }
        float ssum = 0.f;
#pragma unroll
        for (int l = 0; l < 9; ++l) { v[l] = __expf(v[l] - mx); ssum += v[l]; }
        float inv = 1.f / ssum;
        float acc0 = 0.f, acc1 = 0.f;
#pragma unroll
        for (int l = 0; l < 9; ++l) {
            int dy = l / 3 - 1, dx = l % 3 - 1;
            int yy = y + dy, xx = x + dx;
            if (yy >= 0 && yy < 32 && xx >= 0 && xx < 32) {
                float sv = v[l] * inv;
                size_t hidx = (size_t)(l * 256) * NPIX + (size_t)(pix + dy * 32 + dx);
                acc0 += sv * __bfloat162float(hb[hidx]);
                acc1 += sv * __bfloat162float(hb[hidx + NPIX]);
            }
        }
        ob[pix] = acc0;
        ob[HW + pix] = acc1;
    }
}

extern "C" void kernel_launch(void* const* d_in, const int* in_sizes, int n_in,
                              void* d_out, int out_size, void* d_ws, size_t ws_size,
                              hipStream_t stream) {
    const float* x     = (const float*)d_in[0];
    const float* cw    = (const float*)d_in[1];
    const float* gamma = (const float*)d_in[2];
    const float* beta  = (const float*)d_in[3];
    const float* wgt   = (const float*)d_in[4];

    char* ws = (char*)d_ws;
    u16*   Abuf = (u16*)(ws + OFF_A);
    u16*   XT   = (u16*)(ws + OFF_XT);
    u16*   Hm   = (u16*)(ws + OFF_H);
    float* sraw = (float*)(ws + OFF_SRAW);
    float* stats= (float*)(ws + OFF_STAT);

    build_all<<<2314, 256, 0, stream>>>(x, wgt, cw, XT, Abuf, stats);
    gemm_bt<<<19 * 32, 256, 0, stream>>>(Abuf, XT, (__hip_bfloat16*)Hm);
    sigma_stats<<<N_IMG * KK * 4, 256, 0, stream>>>((const __hip_bfloat16*)Hm, sraw, stats);
    tail<<<1024, 256, 0, stream>>>((const __hip_bfloat16*)Hm, sraw, stats, gamma, beta, (float*)d_out);
}